// Round 13
// baseline (4458.487 us; speedup 1.0000x reference)
//
#include <hip/hip_runtime.h>

typedef __bf16 bf16;
typedef __bf16 bf16x8 __attribute__((ext_vector_type(8)));
typedef float f32x4 __attribute__((ext_vector_type(4)));

#define NTOK 16384
#define DMODEL 1024
#define HFFN 4096
#define NEXP 8
#define CAP 2048

#define VMCNT(n) asm volatile("s_waitcnt vmcnt(" #n ")" ::: "memory")
#define BARRIER() __builtin_amdgcn_s_barrier()
#define PRIO1() __builtin_amdgcn_s_setprio(1)
#define PRIO0() __builtin_amdgcn_s_setprio(0)

__device__ __forceinline__ void gload16(const void* g, void* l) {
  __builtin_amdgcn_global_load_lds((const __attribute__((address_space(1))) void*)g,
                                   (__attribute__((address_space(3))) void*)l, 16, 0, 0);
}

// exact tanh-approx gelu via sigmoid identity
__device__ __forceinline__ float gelu_f(float v) {
  float t = v * v;
  float s2 = v * fmaf(0.10294358f, t, 2.3022084f);
  float e = __builtin_exp2f(-s2);
  return v * __builtin_amdgcn_rcpf(1.0f + e);
}

// XCD remap: group same-bx (B-column) on one XCD -> B panel L2-resident.
// bijective for gridDim.x % 8 == 0 (32 or 8 here).
__device__ __forceinline__ void xcd_remap(int& bx, int& by) {
  const int gy = gridDim.y;
  const int w = blockIdx.x + gridDim.x * blockIdx.y;
  const int xcd = w & 7;
  const int idx = w >> 3;
  by = idx % gy;
  bx = (idx / gy) * 8 + xcd;
}

// ---------------- x: f32 -> bf16 ----------------
__global__ __launch_bounds__(256) void cvt_x_kernel(const float* __restrict__ x,
                                                    bf16* __restrict__ xb) {
  int i = blockIdx.x * blockDim.x + threadIdx.x;
  const float4* a = (const float4*)x + (size_t)i * 2;
  float4 v0 = a[0], v1 = a[1];
  bf16x8 o;
  o[0]=(bf16)v0.x; o[1]=(bf16)v0.y; o[2]=(bf16)v0.z; o[3]=(bf16)v0.w;
  o[4]=(bf16)v1.x; o[5]=(bf16)v1.y; o[6]=(bf16)v1.z; o[7]=(bf16)v1.w;
  *(bf16x8*)(xb + (size_t)i * 8) = o;
}

// ---------------- router ----------------
__global__ __launch_bounds__(64) void router_kernel(const float* __restrict__ x,
                                                    const float* __restrict__ gw,
                                                    float* __restrict__ probs) {
  int t = blockIdx.x;
  int l = threadIdx.x;
  int e = l & 7, chunk = l >> 3;
  const float* xr = x + (size_t)t * DMODEL + chunk * 128;
  const float* gwr = gw + (size_t)(chunk * 128) * NEXP + e;
  float a0 = 0.f, a1 = 0.f;
  #pragma unroll
  for (int d = 0; d < 128; d += 8) {
    float4 xv = *(const float4*)(xr + d);
    float4 xw = *(const float4*)(xr + d + 4);
    a0 += xv.x * gwr[(d+0)*8] + xv.y * gwr[(d+1)*8] + xv.z * gwr[(d+2)*8] + xv.w * gwr[(d+3)*8];
    a1 += xw.x * gwr[(d+4)*8] + xw.y * gwr[(d+5)*8] + xw.z * gwr[(d+6)*8] + xw.w * gwr[(d+7)*8];
  }
  float acc = a0 + a1;
  acc += __shfl_xor(acc, 8);
  acc += __shfl_xor(acc, 16);
  acc += __shfl_xor(acc, 32);
  float m = acc;
  m = fmaxf(m, __shfl_xor(m, 1));
  m = fmaxf(m, __shfl_xor(m, 2));
  m = fmaxf(m, __shfl_xor(m, 4));
  float ex = expf(acc - m);
  float s = ex;
  s += __shfl_xor(s, 1); s += __shfl_xor(s, 2); s += __shfl_xor(s, 4);
  if (l < 8) probs[(size_t)e * NTOK + t] = ex / s;
}

// ---------------- per-expert top-2048 radix select ----------------
__global__ __launch_bounds__(256) void topk_kernel(const float* __restrict__ probs,
                                                   int* __restrict__ oidx,
                                                   float* __restrict__ oscr) {
  const int e = blockIdx.x;
  const float* p = probs + (size_t)e * NTOK;
  const int t = threadIdx.x;
  __shared__ unsigned hist[256];
  __shared__ unsigned sg[256], sq[256];
  __shared__ unsigned bcast[4];
  unsigned pref = 0, krem = CAP;
  for (int pass = 0; pass < 4; ++pass) {
    const int sh = 24 - pass * 8;
    hist[t] = 0;
    __syncthreads();
    for (int j = 0; j < 64; ++j) {
      unsigned u = __float_as_uint(p[t * 64 + j]);
      bool ok = (pass == 0) || ((u >> (sh + 8)) == pref);
      if (ok) atomicAdd(&hist[(u >> sh) & 255u], 1u);
    }
    __syncthreads();
    if (t == 0) {
      unsigned cum = 0; int b = 255;
      for (; b > 0; --b) {
        unsigned c = hist[b];
        if (cum + c >= krem) break;
        cum += c;
      }
      bcast[0] = (pref << 8) | (unsigned)b;
      bcast[1] = krem - cum;
    }
    __syncthreads();
    pref = bcast[0];
    krem = bcast[1];
  }
  const unsigned thr = pref;
  const unsigned neq_take = krem;
  unsigned cgt = 0, ceq = 0;
  for (int j = 0; j < 64; ++j) {
    unsigned u = __float_as_uint(p[t * 64 + j]);
    cgt += (u > thr);
    ceq += (u == thr);
  }
  sg[t] = cgt; sq[t] = ceq;
  __syncthreads();
  if (t == 0) {
    unsigned ag = 0, aq = 0;
    for (int i = 0; i < 256; ++i) {
      unsigned g = sg[i], q = sq[i];
      sg[i] = ag; sq[i] = aq;
      ag += g; aq += q;
    }
    bcast[2] = ag;
  }
  __syncthreads();
  const unsigned ngt = bcast[2];
  unsigned og = sg[t], oq = sq[t];
  int* oi = oidx + e * CAP;
  float* os = oscr + e * CAP;
  for (int j = 0; j < 64; ++j) {
    int tok = t * 64 + j;
    float pv = p[tok];
    unsigned u = __float_as_uint(pv);
    if (u > thr) {
      oi[og] = tok; os[og] = pv; ++og;
    } else if (u == thr) {
      if (oq < neq_take) { oi[ngt + oq] = tok; os[ngt + oq] = pv; }
      ++oq;
    }
  }
}

// ---------------- weight transpose + cvt ----------------
__global__ __launch_bounds__(256) void transpose_cvt(const float* __restrict__ in_e,
                                                     const float* __restrict__ in_s,
                                                     bf16* __restrict__ outp,
                                                     int R, int C) {
  int z = blockIdx.z;
  const float* in = (z < 8) ? (in_e + (size_t)z * (size_t)R * C) : in_s;
  bf16* out = outp + (size_t)z * (size_t)R * C;
  __shared__ float tile[64][65];
  int tx = threadIdx.x & 63, ty = threadIdx.x >> 6;
  int c0 = blockIdx.x * 64, r0 = blockIdx.y * 64;
  #pragma unroll
  for (int j = 0; j < 16; ++j) {
    int r = ty + j * 4;
    tile[r][tx] = in[(size_t)(r0 + r) * C + c0 + tx];
  }
  __syncthreads();
  #pragma unroll
  for (int j = 0; j < 16; ++j) {
    int c = ty + j * 4;
    out[(size_t)(c0 + c) * R + r0 + tx] = (bf16)tile[tx][c];
  }
}

// =====================================================================
// Register-heavy GEMM: block = 2 waves (128 thr), tile 256(M)x128(N),
// per-wave output 128x128 (acc 256 VGPR, 1 wave/SIMD), BK=32.
// A staged via gload_lds into a 3-buffer ring (3 x 16KB = 48KB LDS);
// B read DIRECTLY from L2 into registers (w^T layout: lanes l,l+16,
// l+32,l+48 read one 64B line per row -> fully coalesced). 2 blocks/CU.
// Loop: iter t = [read 8 A-frags from ring[t%3]; stage A(t+2);
//   load B(t+1) regs; 64 MFMA; BARRIER].
// Sync proof: B(t)'s register dep makes the compiler emit a vmcnt wait
// before MFMA(t); since stage A(t+1) was issued BEFORE loadB(t) (iter
// t-1), in-order vmem retirement means that wait also retires A(t+1);
// barrier(t) then orders it before any wave's reads at iter t+1.
// Stage(t+2) targets ring[(t-1)%3], whose readers drained pre-BAR(t-1).
// Swizzle (64B rows): chunk ^ (row>>1)&3 — verified 0-conflict (R4+).
// =====================================================================

#define STG_A(D, kt) do { \
  _Pragma("unroll") for (int s = 0; s < 8; ++s) \
    gload16(srcA[s] + (kt) * 32, (D) + s * 1024 + tid * 8); \
} while (0)

#define RD_A(D) do { \
  _Pragma("unroll") for (int i = 0; i < 8; ++i) \
    aA[i] = *(const bf16x8*)((D) + (wave * 128 + i * 16 + fr) * 32 + cS); \
} while (0)

#define LOAD_B(SET, kt) do { \
  _Pragma("unroll") for (int j = 0; j < 8; ++j) \
    SET[j] = *(const bf16x8*)(bP + (size_t)j * jstride + (kt) * 32); \
} while (0)

#define MFMA_ALL(BS) \
  _Pragma("unroll") for (int i = 0; i < 8; ++i) \
    _Pragma("unroll") for (int j = 0; j < 8; ++j) \
      acc[i][j] = __builtin_amdgcn_mfma_f32_16x16x32_bf16(aA[i], BS[j], acc[i][j], 0, 0, 0)

#define KLOOP(KDIM) do { \
  const int NT = (KDIM) / 32; \
  STG_A(smem, 0); \
  STG_A(smem + 8192, 1); \
  LOAD_B(Bc, 0); \
  VMCNT(16); \
  BARRIER(); \
  for (int t = 0; t < NT; t += 2) { \
    /* even iter: uses Bc */ \
    RD_A(smem + (t % 3) * 8192); \
    if (t + 2 < NT) STG_A(smem + ((t + 2) % 3) * 8192, t + 2); \
    if (t + 1 < NT) LOAD_B(Bn, t + 1); \
    PRIO1(); MFMA_ALL(Bc); PRIO0(); \
    BARRIER(); \
    /* odd iter: uses Bn */ \
    RD_A(smem + ((t + 1) % 3) * 8192); \
    if (t + 3 < NT) STG_A(smem + ((t + 3) % 3) * 8192, t + 3); \
    if (t + 2 < NT) LOAD_B(Bc, t + 2); \
    PRIO1(); MFMA_ALL(Bn); PRIO0(); \
    BARRIER(); \
  } \
} while (0)

// ---------------- FFN up GEMM: h = gelu(A @ W1^T + b1) ----------------
__global__ __launch_bounds__(128, 1) void ffn1_gemm(const bf16* __restrict__ xb,
                                                    const bf16* __restrict__ w1t,
                                                    const float* __restrict__ bias1,
                                                    const int* __restrict__ sel,
                                                    bf16* __restrict__ hout,
                                                    int routed) {
  const int e = blockIdx.z;
  const bf16* Bw = w1t + (routed ? (size_t)e * HFFN * DMODEL : 0);
  const float* bias = bias1 + (routed ? (size_t)e * HFFN : 0);
  bf16* hb = hout + (routed ? (size_t)e * CAP * HFFN : 0);
  int bx, by;
  xcd_remap(bx, by);
  const int m0 = by * 256, n0 = bx * 128;
  __shared__ __align__(16) bf16 smem[24576];   // 48 KiB: 3 x (A 256x32)
  const int tid = threadIdx.x, lane = tid & 63, wave = tid >> 6;
  const int fr = lane & 15, k4 = lane >> 4;
  const int cS = (k4 ^ ((fr >> 1) & 3)) * 8;

  // A staging: thread covers rows tid>>2 + 32s, source chunk (tid&3)^((tid>>3)&3)
  const int csrc = (tid & 3) ^ ((tid >> 3) & 3);
  const bf16* srcA[8];
  #pragma unroll
  for (int s = 0; s < 8; ++s) {
    int r = m0 + (tid >> 2) + 32 * s;
    int gr = routed ? sel[e * CAP + r] : r;
    srcA[s] = xb + (size_t)gr * DMODEL + csrc * 8;
  }
  const bf16* bP = Bw + (size_t)(n0 + fr) * DMODEL + k4 * 8;
  const size_t jstride = (size_t)16 * DMODEL;

  f32x4 acc[8][8];
  #pragma unroll
  for (int i = 0; i < 8; ++i)
    #pragma unroll
    for (int j = 0; j < 8; ++j) acc[i][j] = (f32x4){0.f, 0.f, 0.f, 0.f};
  bf16x8 aA[8], Bc[8], Bn[8];

  KLOOP(DMODEL);

  // epilogue: bias+gelu -> bf16; two wave-halves via swizzled LDS bounce
  __syncthreads();
  #pragma unroll
  for (int h = 0; h < 2; ++h) {
    if (wave == h) {
      #pragma unroll
      for (int i = 0; i < 8; ++i) {
        #pragma unroll
        for (int j = 0; j < 8; ++j) {
          const int col = j * 16 + fr;
          const float bb = bias[n0 + col];
          #pragma unroll
          for (int q = 0; q < 4; ++q) {
            const int row = i * 16 + k4 * 4 + q;
            smem[row * 128 + (((col >> 3) ^ (row & 7)) * 8) + (col & 7)] =
                (bf16)gelu_f(acc[i][j][q] + bb);
          }
        }
      }
    }
    __syncthreads();
    #pragma unroll
    for (int p = 0; p < 16; ++p) {
      const int f = p * 128 + tid;
      const int row = f >> 4, c16 = f & 15;
      uint4 v = *(const uint4*)(smem + row * 128 + ((c16 ^ (row & 7)) * 8));
      *(uint4*)(hb + (size_t)(m0 + h * 128 + row) * HFFN + n0 + c16 * 8) = v;
    }
    __syncthreads();
  }
}

// ---------------- FFN down GEMM: y = h @ W2^T + b2 ----------------
__global__ __launch_bounds__(128, 1) void ffn2_gemm(const bf16* __restrict__ hbuf,
                                                    const bf16* __restrict__ w2t,
                                                    const float* __restrict__ bias2,
                                                    const int* __restrict__ sel,
                                                    const float* __restrict__ scr,
                                                    float* __restrict__ out,
                                                    int routed) {
  const int e = blockIdx.z;
  const bf16* Ab = hbuf + (routed ? (size_t)e * CAP * HFFN : 0);
  const bf16* Bw = w2t + (routed ? (size_t)e * DMODEL * HFFN : 0);
  const float* bias = bias2 + (routed ? (size_t)e * DMODEL : 0);
  int bx, by;
  xcd_remap(bx, by);
  const int m0 = by * 256, n0 = bx * 128;
  __shared__ __align__(16) bf16 smem[24576];
  __shared__ int s_tok[256];
  __shared__ float s_scl[256];
  const int tid = threadIdx.x, lane = tid & 63, wave = tid >> 6;
  const int fr = lane & 15, k4 = lane >> 4;
  const int cS = (k4 ^ ((fr >> 1) & 3)) * 8;

  const int csrc = (tid & 3) ^ ((tid >> 3) & 3);
  const bf16* srcA[8];
  #pragma unroll
  for (int s = 0; s < 8; ++s)
    srcA[s] = Ab + (size_t)(m0 + (tid >> 2) + 32 * s) * HFFN + csrc * 8;
  const bf16* bP = Bw + (size_t)(n0 + fr) * HFFN + k4 * 8;
  const size_t jstride = (size_t)16 * HFFN;
  if (routed) {
    s_tok[tid] = sel[e * CAP + m0 + tid];
    s_tok[tid + 128] = sel[e * CAP + m0 + 128 + tid];
    s_scl[tid] = scr[e * CAP + m0 + tid];
    s_scl[tid + 128] = scr[e * CAP + m0 + 128 + tid];
  }

  f32x4 acc[8][8];
  #pragma unroll
  for (int i = 0; i < 8; ++i)
    #pragma unroll
    for (int j = 0; j < 8; ++j) acc[i][j] = (f32x4){0.f, 0.f, 0.f, 0.f};
  bf16x8 aA[8], Bc[8], Bn[8];

  KLOOP(HFFN);

  if (!routed) {
    #pragma unroll
    for (int i = 0; i < 8; ++i) {
      #pragma unroll
      for (int j = 0; j < 8; ++j) {
        const int col = n0 + j * 16 + fr;
        const float bb = bias[col];
        #pragma unroll
        for (int q = 0; q < 4; ++q) {
          const int row = m0 + wave * 128 + i * 16 + k4 * 4 + q;
          out[(size_t)row * DMODEL + col] = acc[i][j][q] + bb;
        }
      }
    }
  } else {
    __syncthreads();
    #pragma unroll
    for (int i = 0; i < 8; ++i) {
      #pragma unroll
      for (int j = 0; j < 8; ++j) {
        const int col = n0 + j * 16 + fr;
        const float bb = bias[col];
        #pragma unroll
        for (int q = 0; q < 4; ++q) {
          const int ml = wave * 128 + i * 16 + k4 * 4 + q;
          const int tok = s_tok[ml];
          const float sc = s_scl[ml];
          atomicAdd(out + (size_t)tok * DMODEL + col, (acc[i][j][q] + bb) * sc);
        }
      }
    }
  }
}

extern "C" void kernel_launch(void* const* d_in, const int* in_sizes, int n_in,
                              void* d_out, int out_size, void* d_ws, size_t ws_size,
                              hipStream_t stream) {
  const float* x   = (const float*)d_in[0];
  const float* gw  = (const float*)d_in[1];
  const float* ew1 = (const float*)d_in[2];
  const float* eb1 = (const float*)d_in[3];
  const float* ew2 = (const float*)d_in[4];
  const float* eb2 = (const float*)d_in[5];
  const float* sw1 = (const float*)d_in[6];
  const float* sb1 = (const float*)d_in[7];
  const float* sw2 = (const float*)d_in[8];
  const float* sb2 = (const float*)d_in[9];
  float* out = (float*)d_out;

  char* ws = (char*)d_ws;
  size_t off = 0;
  bf16* xb      = (bf16*)(ws + off); off += (size_t)NTOK * DMODEL * 2;
  bf16* w1t     = (bf16*)(ws + off); off += (size_t)9 * HFFN * DMODEL * 2;
  bf16* w2t     = (bf16*)(ws + off); off += (size_t)9 * DMODEL * HFFN * 2;
  bf16* hbuf    = (bf16*)(ws + off); off += (size_t)NTOK * HFFN * 2;
  float* probs  = (float*)(ws + off); off += (size_t)NEXP * NTOK * 4;
  int* selidx   = (int*)(ws + off);   off += (size_t)NEXP * CAP * 4;
  float* selscr = (float*)(ws + off); off += (size_t)NEXP * CAP * 4;

  cvt_x_kernel<<<dim3(NTOK * DMODEL / 8 / 256), dim3(256), 0, stream>>>(x, xb);
  router_kernel<<<dim3(NTOK), dim3(64), 0, stream>>>(x, gw, probs);
  topk_kernel<<<dim3(NEXP), dim3(256), 0, stream>>>(probs, selidx, selscr);
  transpose_cvt<<<dim3(HFFN / 64, DMODEL / 64, 9), dim3(256), 0, stream>>>(ew1, sw1, w1t, DMODEL, HFFN);
  transpose_cvt<<<dim3(DMODEL / 64, HFFN / 64, 9), dim3(256), 0, stream>>>(ew2, sw2, w2t, HFFN, DMODEL);

  ffn1_gemm<<<dim3(HFFN / 128, NTOK / 256, 1), dim3(128), 0, stream>>>(
      xb, w1t + (size_t)8 * HFFN * DMODEL, sb1, (const int*)nullptr, hbuf, 0);
  ffn2_gemm<<<dim3(DMODEL / 128, NTOK / 256, 1), dim3(128), 0, stream>>>(
      hbuf, w2t + (size_t)8 * DMODEL * HFFN, sb2, (const int*)nullptr, (const float*)nullptr, out, 0);

  ffn1_gemm<<<dim3(HFFN / 128, CAP / 256, NEXP), dim3(128), 0, stream>>>(
      xb, w1t, eb1, selidx, hbuf, 1);
  ffn2_gemm<<<dim3(DMODEL / 128, CAP / 256, NEXP), dim3(128), 0, stream>>>(
      hbuf, w2t, eb2, selidx, selscr, out, 1);
}

// Round 15
// 835.269 us; speedup vs baseline: 5.3378x; 5.3378x over previous
//
#include <hip/hip_runtime.h>

typedef __bf16 bf16;
typedef __bf16 bf16x4 __attribute__((ext_vector_type(4)));
typedef __bf16 bf16x8 __attribute__((ext_vector_type(8)));
typedef float f32x4 __attribute__((ext_vector_type(4)));

#define NTOK 16384
#define DMODEL 1024
#define HFFN 4096
#define NEXP 8
#define CAP 2048

#define VMCNT(n) asm volatile("s_waitcnt vmcnt(" #n ")" ::: "memory")
#define BARRIER() __builtin_amdgcn_s_barrier()
#define PRIO1() __builtin_amdgcn_s_setprio(1)
#define PRIO0() __builtin_amdgcn_s_setprio(0)

__device__ __forceinline__ void gload16(const void* g, void* l) {
  __builtin_amdgcn_global_load_lds((const __attribute__((address_space(1))) void*)g,
                                   (__attribute__((address_space(3))) void*)l, 16, 0, 0);
}

// exact tanh-approx gelu via sigmoid identity
__device__ __forceinline__ float gelu_f(float v) {
  float t = v * v;
  float s2 = v * fmaf(0.10294358f, t, 2.3022084f);
  float e = __builtin_exp2f(-s2);
  return v * __builtin_amdgcn_rcpf(1.0f + e);
}

__device__ __forceinline__ void xcd_remap(int& bx, int& by) {
  const int gx = gridDim.x;
  const int lg = 31 - __clz((unsigned)gx);
  const int w = blockIdx.x + gx * blockIdx.y;
  bx = (w >> 3) & (gx - 1);
  by = (w & 7) | (((w >> 3) >> lg) << 3);
}

// ---------------- router (+ fused x -> bf16 conversion) ----------------
__global__ __launch_bounds__(64) void router_kernel(const float* __restrict__ x,
                                                    const float* __restrict__ gw,
                                                    float* __restrict__ probs,
                                                    bf16* __restrict__ xb) {
  int t = blockIdx.x;
  int l = threadIdx.x;
  int e = l & 7, chunk = l >> 3;
  const float* xr = x + (size_t)t * DMODEL + chunk * 128;
  const float* gwr = gw + (size_t)(chunk * 128) * NEXP + e;
  float a0 = 0.f, a1 = 0.f;
  #pragma unroll
  for (int d = 0; d < 128; d += 8) {
    float4 xv = *(const float4*)(xr + d);
    float4 xw = *(const float4*)(xr + d + 4);
    a0 += xv.x * gwr[(d+0)*8] + xv.y * gwr[(d+1)*8] + xv.z * gwr[(d+2)*8] + xv.w * gwr[(d+3)*8];
    a1 += xw.x * gwr[(d+4)*8] + xw.y * gwr[(d+5)*8] + xw.z * gwr[(d+6)*8] + xw.w * gwr[(d+7)*8];
  }
  float acc = a0 + a1;
  acc += __shfl_xor(acc, 8);
  acc += __shfl_xor(acc, 16);
  acc += __shfl_xor(acc, 32);
  float m = acc;
  m = fmaxf(m, __shfl_xor(m, 1));
  m = fmaxf(m, __shfl_xor(m, 2));
  m = fmaxf(m, __shfl_xor(m, 4));
  float ex = expf(acc - m);
  float s = ex;
  s += __shfl_xor(s, 1); s += __shfl_xor(s, 2); s += __shfl_xor(s, 4);
  if (l < 8) probs[(size_t)e * NTOK + t] = ex / s;

  // fused cvt: lane l converts elems [l*16, l*16+16) of this token row
  const float4* xr4 = (const float4*)(x + (size_t)t * DMODEL) + l * 4;
  float4 v0 = xr4[0], v1 = xr4[1], v2 = xr4[2], v3 = xr4[3];
  bf16x8 o0, o1;
  o0[0]=(bf16)v0.x; o0[1]=(bf16)v0.y; o0[2]=(bf16)v0.z; o0[3]=(bf16)v0.w;
  o0[4]=(bf16)v1.x; o0[5]=(bf16)v1.y; o0[6]=(bf16)v1.z; o0[7]=(bf16)v1.w;
  o1[0]=(bf16)v2.x; o1[1]=(bf16)v2.y; o1[2]=(bf16)v2.z; o1[3]=(bf16)v2.w;
  o1[4]=(bf16)v3.x; o1[5]=(bf16)v3.y; o1[6]=(bf16)v3.z; o1[7]=(bf16)v3.w;
  bf16* xo = xb + (size_t)t * DMODEL + l * 16;
  *(bf16x8*)xo = o0;
  *(bf16x8*)(xo + 8) = o1;
}

// ---------------- per-expert top-2048 radix select ----------------
__global__ __launch_bounds__(256) void topk_kernel(const float* __restrict__ probs,
                                                   int* __restrict__ oidx,
                                                   float* __restrict__ oscr) {
  const int e = blockIdx.x;
  const float* p = probs + (size_t)e * NTOK;
  const int t = threadIdx.x;
  __shared__ unsigned hist[256];
  __shared__ unsigned sg[256], sq[256];
  __shared__ unsigned bcast[4];
  unsigned pref = 0, krem = CAP;
  for (int pass = 0; pass < 4; ++pass) {
    const int sh = 24 - pass * 8;
    hist[t] = 0;
    __syncthreads();
    for (int j = 0; j < 64; ++j) {
      unsigned u = __float_as_uint(p[t * 64 + j]);
      bool ok = (pass == 0) || ((u >> (sh + 8)) == pref);
      if (ok) atomicAdd(&hist[(u >> sh) & 255u], 1u);
    }
    __syncthreads();
    if (t == 0) {
      unsigned cum = 0; int b = 255;
      for (; b > 0; --b) {
        unsigned c = hist[b];
        if (cum + c >= krem) break;
        cum += c;
      }
      bcast[0] = (pref << 8) | (unsigned)b;
      bcast[1] = krem - cum;
    }
    __syncthreads();
    pref = bcast[0];
    krem = bcast[1];
  }
  const unsigned thr = pref;
  const unsigned neq_take = krem;
  unsigned cgt = 0, ceq = 0;
  for (int j = 0; j < 64; ++j) {
    unsigned u = __float_as_uint(p[t * 64 + j]);
    cgt += (u > thr);
    ceq += (u == thr);
  }
  sg[t] = cgt; sq[t] = ceq;
  __syncthreads();
  if (t == 0) {
    unsigned ag = 0, aq = 0;
    for (int i = 0; i < 256; ++i) {
      unsigned g = sg[i], q = sq[i];
      sg[i] = ag; sq[i] = aq;
      ag += g; aq += q;
    }
    bcast[2] = ag;
  }
  __syncthreads();
  const unsigned ngt = bcast[2];
  unsigned og = sg[t], oq = sq[t];
  int* oi = oidx + e * CAP;
  float* os = oscr + e * CAP;
  for (int j = 0; j < 64; ++j) {
    int tok = t * 64 + j;
    float pv = p[tok];
    unsigned u = __float_as_uint(pv);
    if (u > thr) {
      oi[og] = tok; os[og] = pv; ++og;
    } else if (u == thr) {
      if (oq < neq_take) { oi[ngt + oq] = tok; os[ngt + oq] = pv; }
      ++oq;
    }
  }
}

// ---------------- weight transpose + cvt (vectorized stores) ----------------
__global__ __launch_bounds__(256) void transpose_cvt(const float* __restrict__ in_e,
                                                     const float* __restrict__ in_s,
                                                     bf16* __restrict__ outp,
                                                     int R, int C) {
  int z = blockIdx.z;
  const float* in = (z < 8) ? (in_e + (size_t)z * (size_t)R * C) : in_s;
  bf16* out = outp + (size_t)z * (size_t)R * C;
  __shared__ float tile[64][65];
  int tx = threadIdx.x & 63, ty = threadIdx.x >> 6;
  int c0 = blockIdx.x * 64, r0 = blockIdx.y * 64;
  #pragma unroll
  for (int j = 0; j < 16; ++j) {
    int r = ty + j * 4;
    tile[r][tx] = in[(size_t)(r0 + r) * C + c0 + tx];
  }
  __syncthreads();
  const int rr4 = (threadIdx.x & 15) * 4;
  #pragma unroll
  for (int j = 0; j < 4; ++j) {
    const int c = (threadIdx.x >> 4) + j * 16;
    bf16x4 o;
    o[0] = (bf16)tile[rr4 + 0][c];
    o[1] = (bf16)tile[rr4 + 1][c];
    o[2] = (bf16)tile[rr4 + 2][c];
    o[3] = (bf16)tile[rr4 + 3][c];
    *(bf16x4*)(out + (size_t)(c0 + c) * R + r0 + rr4) = o;
  }
}

// =====================================================================
// R12 GEMM (verbatim — verified identity-consistent layout, benched
// PASS @ 835 µs): 256x256 tile, BK=64, 512 thr, 2 LDS buffers,
// 3 barriers / K-tile.
//   P0: read cur.{Alo,Blo,Bhi} (16 b128); stage nxt.Ahi(t+1); BAR1;
//       q00+q01 (32 MFMA).
//   P1: read cur.Ahi (8); BAR2.
//   P2: stage cur.{Alo,Blo,Bhi}(t+2); q10+q11 (32 MFMA); VMCNT(6); BAR3.
// Gate ledger: outstanding at gate = prevP2 6 + thisP0 2 + thisP2 6
// = 14; VMCNT(6) retires exactly tile t+1's 8. Region safety by
// drain-point + barrier transitivity (see R12 notes).
// =====================================================================

#define STG_ALO(D, ko) { gload16(srcA0 + (ko), (D) + tid8); gload16(srcA2 + (ko), (D) + 4096 + tid8); }
#define STG_AHI(D, ko) { gload16(srcA1 + (ko), (D) + 8192 + tid8); gload16(srcA3 + (ko), (D) + 12288 + tid8); }
#define STG_BLO(D, ko) { gload16(srcBlo0 + (ko), (D) + 16384 + tid8); gload16(srcBlo1 + (ko), (D) + 20480 + tid8); }
#define STG_BHI(D, ko) { gload16(srcBhi0 + (ko), (D) + 24576 + tid8); gload16(srcBhi1 + (ko), (D) + 28672 + tid8); }

#define RD_A(ARR, D, OFF) \
  _Pragma("unroll") for (int i = 0; i < 4; ++i) { \
    ARR[2*i]   = *(const bf16x8*)((D) + (OFF) + (wr*64 + i*16 + fr)*64 + c0s); \
    ARR[2*i+1] = *(const bf16x8*)((D) + (OFF) + (wr*64 + i*16 + fr)*64 + c1s); \
  }
#define RD_B(ARR, D, OFF) \
  _Pragma("unroll") for (int j = 0; j < 2; ++j) { \
    ARR[2*j]   = *(const bf16x8*)((D) + (OFF) + (wc*32 + j*16 + fr)*64 + c0s); \
    ARR[2*j+1] = *(const bf16x8*)((D) + (OFF) + (wc*32 + j*16 + fr)*64 + c1s); \
  }

#define MFMA_Q(I0, J0, A, B) \
  _Pragma("unroll") for (int i = 0; i < 4; ++i) \
    _Pragma("unroll") for (int j = 0; j < 2; ++j) { \
      acc[(I0)+i][(J0)+j] = __builtin_amdgcn_mfma_f32_16x16x32_bf16((A)[2*i],   (B)[2*j],   acc[(I0)+i][(J0)+j], 0, 0, 0); \
      acc[(I0)+i][(J0)+j] = __builtin_amdgcn_mfma_f32_16x16x32_bf16((A)[2*i+1], (B)[2*j+1], acc[(I0)+i][(J0)+j], 0, 0, 0); \
    }

#define KLOOP(NT) do { \
  bf16* B0_ = smem; \
  bf16* B1_ = smem + 32768; \
  STG_ALO(B0_, 0); STG_AHI(B0_, 0); STG_BLO(B0_, 0); STG_BHI(B0_, 0); \
  STG_ALO(B1_, 64); STG_BLO(B1_, 64); STG_BHI(B1_, 64); \
  VMCNT(6); \
  BARRIER(); \
  for (int t = 0; t < (NT); ++t) { \
    bf16* cur = smem + ((t & 1) << 15); \
    bf16* nxt = smem + (((t + 1) & 1) << 15); \
    const int ko1 = (t + 1) * 64, ko2 = (t + 2) * 64; \
    const bool st1 = (t + 1) < (NT), st2 = (t + 2) < (NT); \
    bf16x8 aA[8], S1[4], S2[4]; \
    /* ---- P0 ---- */ \
    RD_A(aA, cur, 0); \
    RD_B(S1, cur, 16384); \
    RD_B(S2, cur, 24576); \
    if (st1) STG_AHI(nxt, ko1); \
    BARRIER(); \
    PRIO1(); MFMA_Q(0,0,aA,S1); MFMA_Q(0,2,aA,S2); PRIO0(); \
    /* ---- P1 ---- */ \
    RD_A(aA, cur, 8192); \
    BARRIER(); \
    /* ---- P2 ---- */ \
    if (st2) { STG_ALO(cur, ko2); STG_BLO(cur, ko2); STG_BHI(cur, ko2); } \
    PRIO1(); MFMA_Q(4,0,aA,S1); MFMA_Q(4,2,aA,S2); PRIO0(); \
    if (st2) { VMCNT(6); } else { VMCNT(0); } \
    BARRIER(); \
  } \
} while (0)

// ---------------- FFN up GEMM: h = gelu(A @ W1^T + b1) ----------------
__global__ __launch_bounds__(512, 2) void ffn1_gemm(const bf16* __restrict__ xb,
                                                    const bf16* __restrict__ w1t,
                                                    const float* __restrict__ bias1,
                                                    const int* __restrict__ sel,
                                                    bf16* __restrict__ hout,
                                                    int routed) {
  const int e = blockIdx.z;
  const bf16* Bw = w1t + (routed ? (size_t)e * HFFN * DMODEL : 0);
  const float* bias = bias1 + (routed ? (size_t)e * HFFN : 0);
  bf16* hb = hout + (routed ? (size_t)e * CAP * HFFN : 0);
  int bx, by;
  xcd_remap(bx, by);
  const int m0 = by * 256, n0 = bx * 256;
  __shared__ __align__(16) bf16 smem[65536];   // 128 KiB
  const int tid = threadIdx.x, lane = tid & 63, wave = tid >> 6;
  const int wr = wave >> 2, wc = wave & 3;
  const int tid8 = tid * 8;

  const int p = tid >> 3, sch = tid & 7;
  const int schs = sch ^ (p & 7);
  const int brow = p + (p & 32);
  const bf16 *srcA0, *srcA1, *srcA2, *srcA3, *srcBlo0, *srcBlo1, *srcBhi0, *srcBhi1;
  {
    int ra0 = routed ? sel[e * CAP + m0 + p]       : (m0 + p);
    int ra1 = routed ? sel[e * CAP + m0 + 64 + p]  : (m0 + 64 + p);
    int ra2 = routed ? sel[e * CAP + m0 + 128 + p] : (m0 + 128 + p);
    int ra3 = routed ? sel[e * CAP + m0 + 192 + p] : (m0 + 192 + p);
    srcA0 = xb + (size_t)ra0 * DMODEL + schs * 8;
    srcA1 = xb + (size_t)ra1 * DMODEL + schs * 8;
    srcA2 = xb + (size_t)ra2 * DMODEL + schs * 8;
    srcA3 = xb + (size_t)ra3 * DMODEL + schs * 8;
    srcBlo0 = Bw + (size_t)(n0 + brow) * DMODEL + schs * 8;
    srcBlo1 = srcBlo0 + (size_t)128 * DMODEL;
    srcBhi0 = srcBlo0 + (size_t)32 * DMODEL;
    srcBhi1 = srcBlo0 + (size_t)160 * DMODEL;
  }

  f32x4 acc[8][4];
  #pragma unroll
  for (int i = 0; i < 8; ++i)
    #pragma unroll
    for (int j = 0; j < 4; ++j) acc[i][j] = (f32x4){0.f, 0.f, 0.f, 0.f};

  const int fr = lane & 15;
  const int k8 = lane >> 4;
  const int sw = lane & 7;
  const int c0s = (k8 ^ sw) * 8;
  const int c1s = ((k8 + 4) ^ sw) * 8;

  KLOOP(DMODEL / 64);

  // epilogue: bias+gelu -> bf16, two 128-row halves via swizzled LDS bounce
  __syncthreads();
  #pragma unroll
  for (int half = 0; half < 2; ++half) {
    if (wr == half) {
      #pragma unroll
      for (int i = 0; i < 8; ++i) {
        #pragma unroll
        for (int j = 0; j < 4; ++j) {
          const int nl = wc * 64 + j * 16 + fr;
          const float bb = bias[n0 + nl];
          #pragma unroll
          for (int q = 0; q < 4; ++q) {
            const int ml = i * 16 + (lane >> 4) * 4 + q;
            smem[ml * 256 + (nl ^ (((ml >> 2) & 7) << 4))] =
                (bf16)gelu_f(acc[i][j][q] + bb);
          }
        }
      }
    }
    __syncthreads();
    #pragma unroll
    for (int pp = 0; pp < 8; ++pp) {
      const int flat = pp * 512 + tid;
      const int row = flat >> 5, nc8 = flat & 31;
      uint4 v = *(const uint4*)(smem + row * 256 + ((nc8 * 8) ^ (((row >> 2) & 7) << 4)));
      *(uint4*)(hb + (size_t)(m0 + half * 128 + row) * HFFN + n0 + nc8 * 8) = v;
    }
    __syncthreads();
  }
}

// ---------------- FFN down GEMM: y = h @ W2^T + b2 ----------------
__global__ __launch_bounds__(512, 2) void ffn2_gemm(const bf16* __restrict__ hbuf,
                                                    const bf16* __restrict__ w2t,
                                                    const float* __restrict__ bias2,
                                                    const int* __restrict__ sel,
                                                    const float* __restrict__ scr,
                                                    float* __restrict__ out,
                                                    int routed) {
  const int e = blockIdx.z;
  const bf16* Ab = hbuf + (routed ? (size_t)e * CAP * HFFN : 0);
  const bf16* Bw = w2t + (routed ? (size_t)e * DMODEL * HFFN : 0);
  const float* bias = bias2 + (routed ? (size_t)e * DMODEL : 0);
  int bx, by;
  xcd_remap(bx, by);
  const int m0 = by * 256, n0 = bx * 256;
  __shared__ __align__(16) bf16 smem[65536];
  __shared__ int s_tok[256];
  __shared__ float s_scl[256];
  const int tid = threadIdx.x, lane = tid & 63, wave = tid >> 6;
  const int wr = wave >> 2, wc = wave & 3;
  const int tid8 = tid * 8;

  const int p = tid >> 3, sch = tid & 7;
  const int schs = sch ^ (p & 7);
  const int brow = p + (p & 32);
  const bf16* srcA0 = Ab + (size_t)(m0 + p) * HFFN + schs * 8;
  const bf16* srcA1 = Ab + (size_t)(m0 + 64 + p) * HFFN + schs * 8;
  const bf16* srcA2 = Ab + (size_t)(m0 + 128 + p) * HFFN + schs * 8;
  const bf16* srcA3 = Ab + (size_t)(m0 + 192 + p) * HFFN + schs * 8;
  const bf16* srcBlo0 = Bw + (size_t)(n0 + brow) * HFFN + schs * 8;
  const bf16* srcBlo1 = srcBlo0 + (size_t)128 * HFFN;
  const bf16* srcBhi0 = srcBlo0 + (size_t)32 * HFFN;
  const bf16* srcBhi1 = srcBlo0 + (size_t)160 * HFFN;
  if (routed && tid < 256) {
    s_tok[tid] = sel[e * CAP + m0 + tid];
    s_scl[tid] = scr[e * CAP + m0 + tid];
  }

  f32x4 acc[8][4];
  #pragma unroll
  for (int i = 0; i < 8; ++i)
    #pragma unroll
    for (int j = 0; j < 4; ++j) acc[i][j] = (f32x4){0.f, 0.f, 0.f, 0.f};

  const int fr = lane & 15;
  const int k8 = lane >> 4;
  const int sw = lane & 7;
  const int c0s = (k8 ^ sw) * 8;
  const int c1s = ((k8 + 4) ^ sw) * 8;

  KLOOP(HFFN / 64);

  if (!routed) {
    #pragma unroll
    for (int i = 0; i < 8; ++i) {
      #pragma unroll
      for (int j = 0; j < 4; ++j) {
        const int nl = wc * 64 + j * 16 + fr;
        const float bb = bias[n0 + nl];
        #pragma unroll
        for (int q = 0; q < 4; ++q) {
          const int ml = wr * 128 + i * 16 + (lane >> 4) * 4 + q;
          out[(size_t)(m0 + ml) * DMODEL + n0 + nl] = acc[i][j][q] + bb;
        }
      }
    }
  } else {
    __syncthreads();
    #pragma unroll
    for (int i = 0; i < 8; ++i) {
      #pragma unroll
      for (int j = 0; j < 4; ++j) {
        const int nl = wc * 64 + j * 16 + fr;
        const float bb = bias[n0 + nl];
        #pragma unroll
        for (int q = 0; q < 4; ++q) {
          const int ml = wr * 128 + i * 16 + (lane >> 4) * 4 + q;
          const int tok = s_tok[ml];
          const float sc = s_scl[ml];
          atomicAdd(out + (size_t)tok * DMODEL + n0 + nl, (acc[i][j][q] + bb) * sc);
        }
      }
    }
  }
}

extern "C" void kernel_launch(void* const* d_in, const int* in_sizes, int n_in,
                              void* d_out, int out_size, void* d_ws, size_t ws_size,
                              hipStream_t stream) {
  const float* x   = (const float*)d_in[0];
  const float* gw  = (const float*)d_in[1];
  const float* ew1 = (const float*)d_in[2];
  const float* eb1 = (const float*)d_in[3];
  const float* ew2 = (const float*)d_in[4];
  const float* eb2 = (const float*)d_in[5];
  const float* sw1 = (const float*)d_in[6];
  const float* sb1 = (const float*)d_in[7];
  const float* sw2 = (const float*)d_in[8];
  const float* sb2 = (const float*)d_in[9];
  float* out = (float*)d_out;

  char* ws = (char*)d_ws;
  size_t off = 0;
  bf16* xb      = (bf16*)(ws + off); off += (size_t)NTOK * DMODEL * 2;
  bf16* w1t     = (bf16*)(ws + off); off += (size_t)9 * HFFN * DMODEL * 2;
  bf16* w2t     = (bf16*)(ws + off); off += (size_t)9 * DMODEL * HFFN * 2;
  bf16* hbuf    = (bf16*)(ws + off); off += (size_t)NTOK * HFFN * 2;
  float* probs  = (float*)(ws + off); off += (size_t)NEXP * NTOK * 4;
  int* selidx   = (int*)(ws + off);   off += (size_t)NEXP * CAP * 4;
  float* selscr = (float*)(ws + off); off += (size_t)NEXP * CAP * 4;

  router_kernel<<<dim3(NTOK), dim3(64), 0, stream>>>(x, gw, probs, xb);
  topk_kernel<<<dim3(NEXP), dim3(256), 0, stream>>>(probs, selidx, selscr);
  transpose_cvt<<<dim3(HFFN / 64, DMODEL / 64, 9), dim3(256), 0, stream>>>(ew1, sw1, w1t, DMODEL, HFFN);
  transpose_cvt<<<dim3(DMODEL / 64, HFFN / 64, 9), dim3(256), 0, stream>>>(ew2, sw2, w2t, HFFN, DMODEL);

  ffn1_gemm<<<dim3(HFFN / 256, NTOK / 256, 1), dim3(512), 0, stream>>>(
      xb, w1t + (size_t)8 * HFFN * DMODEL, sb1, (const int*)nullptr, hbuf, 0);
  ffn2_gemm<<<dim3(DMODEL / 256, NTOK / 256, 1), dim3(512), 0, stream>>>(
      hbuf, w2t + (size_t)8 * DMODEL * HFFN, sb2, (const int*)nullptr, (const float*)nullptr, out, 0);

  ffn1_gemm<<<dim3(HFFN / 256, CAP / 256, NEXP), dim3(512), 0, stream>>>(
      xb, w1t, eb1, selidx, hbuf, 1);
  ffn2_gemm<<<dim3(DMODEL / 256, CAP / 256, NEXP), dim3(512), 0, stream>>>(
      hbuf, w2t, eb2, selidx, selscr, out, 1);
}